// Round 3
// baseline (46.133 us; speedup 1.0000x reference)
//
#include <hip/hip_runtime.h>

#define BN_EPS 1e-5f

// Single fused kernel. Dependency cone of the only consumed output position:
//   out(8,8,8) <- x2[15..17]^3 (64ch) <- x1[29..35]^3 (32ch) <- voxel[28..36]^3
// All interior (no padding logic). One block per batch; everything in LDS.
//
// Decompositions (all LDS-conflict-free by construction):
//   conv1: thread per output element, s_in stride-1 reads.
//   conv2: lane owns (co, ci&15); ci and ci+16 accumulated serially;
//          s_x1 addr = 343*ci + C -> bank 23*ci mod 32 (bijective over 16 ci,
//          duplicate ci sets across the wave's 4 groups broadcast).
//          4-step __shfl_xor reduce within 16-lane group.
//   conv3: 16-lane group per co, coalesced float4 over the contiguous
//          1728-float w3 row, 4-step reduce.
//   FC:    lane = output feature (coalesced wp), 4-way ci split via LDS.
__global__ __launch_bounds__(1024) void backbone_fused_kernel(
    const float* __restrict__ voxel,
    const float* __restrict__ w1, const float* __restrict__ g1,
    const float* __restrict__ b1, const float* __restrict__ m1, const float* __restrict__ v1,
    const float* __restrict__ w2, const float* __restrict__ g2,
    const float* __restrict__ b2, const float* __restrict__ m2, const float* __restrict__ v2,
    const float* __restrict__ w3, const float* __restrict__ g3,
    const float* __restrict__ b3, const float* __restrict__ m3, const float* __restrict__ v3,
    const float* __restrict__ wp, const float* __restrict__ bp,
    float* __restrict__ out)
{
    const int b   = blockIdx.x;
    const int tid = threadIdx.x;

    __shared__ __align__(16) float s_in[729];    // 9^3 input patch
    __shared__ float s_w1[864];                  // 32 x 27
    __shared__ __align__(16) float s_x1[10976];  // [32 ci][7^3]
    __shared__ __align__(16) float s_x2[1728];   // [64 ci][27]
    __shared__ float s_x3[128];
    __shared__ float s_fc[1024];                 // FC partials [4][256]
    __shared__ float sa1[32], ss1[32];
    __shared__ float sa2[64], ss2[64];
    __shared__ float sa3[128], ss3[128];

    // ---- Phase 0: stage input patch, conv1 weights, folded BN constants ----
    const float* vb = voxel + (size_t)b * 262144;
    if (tid < 729) {
        int z = tid / 81, r = tid % 81, y = r / 9, x = r % 9;
        s_in[tid] = vb[(28 + z) * 4096 + (28 + y) * 64 + (28 + x)];
    }
    if (tid < 864) s_w1[tid] = w1[tid];
    if (tid >= 896) {                       // 128 ch of stage 3
        int c = tid - 896;
        float a = g3[c] * rsqrtf(v3[c] + BN_EPS);
        sa3[c] = a; ss3[c] = b3[c] - m3[c] * a;
    } else if (tid >= 832) {                // hmm: 64 ch of stage 2
        int c = tid - 832;
        float a = g2[c] * rsqrtf(v2[c] + BN_EPS);
        sa2[c] = a; ss2[c] = b2[c] - m2[c] * a;
    } else if (tid >= 800) {                // 32 ch of stage 1
        int c = tid - 800;
        float a = g1[c] * rsqrtf(v1[c] + BN_EPS);
        sa1[c] = a; ss1[c] = b1[c] - m1[c] * a;
    }
    __syncthreads();

    // ---- Phase 1: conv1 (stride 1) + BN + ReLU -> s_x1[co][7^3] ----
    for (int t = tid; t < 10976; t += 1024) {
        int co = t / 343, r = t % 343;
        int z = r / 49, y = (r / 7) % 7, x = r % 7;
        const float* wc = &s_w1[co * 27];
        float acc = 0.f;
        #pragma unroll
        for (int kd = 0; kd < 3; ++kd)
        #pragma unroll
        for (int kh = 0; kh < 3; ++kh)
        #pragma unroll
        for (int kw = 0; kw < 3; ++kw)
            acc += s_in[(z + kd) * 81 + (y + kh) * 9 + (x + kw)]
                 * wc[kd * 9 + kh * 3 + kw];
        s_x1[t] = fmaxf(acc * sa1[co] + ss1[co], 0.f);
    }
    __syncthreads();

    // ---- Phase 2: conv2 (stride 2) + BN + ReLU -> s_x2[co][27] ----
    {
        const int co = tid >> 4;      // 0..63
        const int j  = tid & 15;      // lane in group = base input channel
        float p[27];
        #pragma unroll
        for (int q = 0; q < 27; ++q) p[q] = 0.f;

        #pragma unroll
        for (int half = 0; half < 2; ++half) {
            const int ci = j + 16 * half;
            float wr[27];
            const float* wg = w2 + ((size_t)co * 32 + ci) * 27;
            #pragma unroll
            for (int k = 0; k < 27; ++k) wr[k] = wg[k];
            const float* xb = &s_x1[ci * 343];
            #pragma unroll
            for (int i = 0; i < 3; ++i)
            #pragma unroll
            for (int jj = 0; jj < 3; ++jj)
            #pragma unroll
            for (int k = 0; k < 3; ++k) {
                float acc = 0.f;
                #pragma unroll
                for (int kd = 0; kd < 3; ++kd)
                #pragma unroll
                for (int kh = 0; kh < 3; ++kh)
                #pragma unroll
                for (int kw = 0; kw < 3; ++kw)
                    acc += xb[(2*i + kd) * 49 + (2*jj + kh) * 7 + (2*k + kw)]
                         * wr[kd * 9 + kh * 3 + kw];
                p[i * 9 + jj * 3 + k] += acc;
            }
        }

        #pragma unroll
        for (int q = 0; q < 27; ++q) {
            p[q] += __shfl_xor(p[q], 1);
            p[q] += __shfl_xor(p[q], 2);
            p[q] += __shfl_xor(p[q], 4);
            p[q] += __shfl_xor(p[q], 8);
        }
        if (j == 0) {
            float a = sa2[co], s = ss2[co];
            #pragma unroll
            for (int q = 0; q < 27; ++q)
                s_x2[co * 27 + q] = fmaxf(p[q] * a + s, 0.f);
        }
    }
    __syncthreads();

    // ---- Phase 3: conv3 center + BN + ReLU -> s_x3[128] ----
    {
        const int g = tid >> 4;       // 0..63
        const int j = tid & 15;
        const float4* xv = (const float4*)s_x2;
        #pragma unroll
        for (int cc = 0; cc < 2; ++cc) {
            const int co = g + 64 * cc;
            const float4* wv = (const float4*)(w3 + (size_t)co * 1728);
            float acc = 0.f;
            #pragma unroll
            for (int t = 0; t < 27; ++t) {
                float4 w4 = wv[j + 16 * t];
                float4 x4 = xv[j + 16 * t];
                acc += w4.x * x4.x + w4.y * x4.y + w4.z * x4.z + w4.w * x4.w;
            }
            acc += __shfl_xor(acc, 1);
            acc += __shfl_xor(acc, 2);
            acc += __shfl_xor(acc, 4);
            acc += __shfl_xor(acc, 8);
            if (j == 0)
                s_x3[co] = fmaxf(acc * sa3[co] + ss3[co], 0.f);
        }
    }
    __syncthreads();

    // ---- Phase 4: FC, coalesced over features, 4-way ci split ----
    {
        const int q = tid >> 8;       // 0..3
        const int f = tid & 255;
        float acc = 0.f;
        #pragma unroll
        for (int c = 0; c < 32; ++c) {
            int ci = q * 32 + c;
            acc += s_x3[ci] * wp[ci * 256 + f];
        }
        s_fc[q * 256 + f] = acc;
    }
    __syncthreads();
    if (tid < 256) {
        out[b * 256 + tid] = bp[tid] + s_fc[tid] + s_fc[256 + tid]
                           + s_fc[512 + tid] + s_fc[768 + tid];
    }
}

extern "C" void kernel_launch(void* const* d_in, const int* in_sizes, int n_in,
                              void* d_out, int out_size, void* d_ws, size_t ws_size,
                              hipStream_t stream) {
    const float* voxel = (const float*)d_in[0];
    const float* w1 = (const float*)d_in[1];
    const float* g1 = (const float*)d_in[2];
    const float* b1 = (const float*)d_in[3];
    const float* m1 = (const float*)d_in[4];
    const float* v1 = (const float*)d_in[5];
    const float* w2 = (const float*)d_in[6];
    const float* g2 = (const float*)d_in[7];
    const float* b2 = (const float*)d_in[8];
    const float* m2 = (const float*)d_in[9];
    const float* v2 = (const float*)d_in[10];
    const float* w3 = (const float*)d_in[11];
    const float* g3 = (const float*)d_in[12];
    const float* b3 = (const float*)d_in[13];
    const float* m3 = (const float*)d_in[14];
    const float* v3 = (const float*)d_in[15];
    const float* wp = (const float*)d_in[16];
    const float* bp = (const float*)d_in[17];
    float* out = (float*)d_out;

    backbone_fused_kernel<<<16, 1024, 0, stream>>>(
        voxel, w1, g1, b1, m1, v1, w2, g2, b2, m2, v2,
        w3, g3, b3, m3, v3, wp, bp, out);
}